// Round 3
// baseline (155.374 us; speedup 1.0000x reference)
//
#include <hip/hip_runtime.h>
#include <math.h>

#define B_ 512
#define T_ 256
#define I_ 7
#define H_ 64
#define L_ 16
#define NCH_ (T_ / L_)
#define L2E 1.44269504089f
#define GUARD2 (-21.64f)

typedef short bf16x8 __attribute__((ext_vector_type(8)));
typedef short short4v __attribute__((ext_vector_type(4)));
typedef float f32x4 __attribute__((ext_vector_type(4)));

__device__ __forceinline__ unsigned short f2bf(float f) {
  unsigned u = __float_as_uint(f);
  u += 0x7fff + ((u >> 16) & 1);          // RNE
  return (unsigned short)(u >> 16);
}
__device__ __forceinline__ float ex2(float x) { return __builtin_amdgcn_exp2f(x); }
__device__ __forceinline__ float lg2(float x) { return __builtin_amdgcn_logf(x); }
// log2(sigmoid(a)) given a already scaled by log2e
__device__ __forceinline__ float logsig2(float a2) {
  return (a2 < GUARD2) ? a2 : -lg2(1.f + ex2(-a2));
}
__device__ __forceinline__ float sig2(float a2) {
  return __fdividef(1.f, 1.f + ex2(-a2));
}

// ---- producer work packs (produce chunk into BUF from x-pointer XP) ----
// w4/w5: i,k,v + own f-half. k~ = ik*2^{m-cl_s}; m=cl[7]. For the upper half the
// exponent is -(partial prefix of ls[8..s]) -- no cross-half dependency.
#define PRODUCE_IKV(BUF, XP) do {                                             \
  float ls8[8], ik8[8];                                                       \
  unsigned short kv[8], vv[8];                                                \
  _Pragma("unroll") for (int tt = 0; tt < 8; ++tt) {                          \
    const int t = tb + tt;                                                    \
    float xs[7];                                                              \
    _Pragma("unroll") for (int jj = 0; jj < 7; ++jj) xs[jj] = (XP)[t * 7 + jj]; \
    float fp = bF2, ip = bI2, kp = bK, vp = bV;                               \
    _Pragma("unroll") for (int jj = 0; jj < 7; ++jj) {                        \
      fp = fmaf(xs[jj], wf2[jj], fp); ip = fmaf(xs[jj], wi2[jj], ip);         \
      kp = fmaf(xs[jj], wk[jj], kp);  vp = fmaf(xs[jj], wv[jj], vp);          \
    }                                                                         \
    ls8[tt] = logsig2(fp);                                                    \
    const float ikv = ex2(ip) * kp * 0.125f;                                  \
    ik8[tt] = ikv;                                                            \
    sIK[BUF][t][lane] = ikv;                                                  \
    vv[tt] = f2bf(vp);                                                        \
  }                                                                           \
  _Pragma("unroll") for (int tt = 1; tt < 8; ++tt) ls8[tt] += ls8[tt - 1];    \
  _Pragma("unroll") for (int tt = 0; tt < 8; ++tt) {                          \
    const float e = (tb == 0) ? (ls8[7] - ls8[tt]) : (-ls8[tt]);              \
    const float u = ik8[tt] * ex2(e);                                         \
    kv[tt] = f2bf(u);                                                         \
    sKt[BUF][tb + tt][lane] = kv[tt];                                         \
  }                                                                           \
  { short4v p0 = {(short)kv[0], (short)kv[1], (short)kv[2], (short)kv[3]};    \
    short4v p1 = {(short)kv[4], (short)kv[5], (short)kv[6], (short)kv[7]};    \
    *(short4v*)&sKnT[BUF][lane][tb]     = p0;                                 \
    *(short4v*)&sKnT[BUF][lane][tb + 4] = p1;                                 \
    short4v q0 = {(short)vv[0], (short)vv[1], (short)vv[2], (short)vv[3]};    \
    short4v q1 = {(short)vv[4], (short)vv[5], (short)vv[6], (short)vv[7]};    \
    *(short4v*)&sVT[BUF][lane][tb]     = q0;                                  \
    *(short4v*)&sVT[BUF][lane][tb + 4] = q1; }                                \
} while (0)

// w6: f-gate (sigmoid values for the n-scan, per-channel chunk scales) + Sq
// (distributed: lane tq computes Sq for t=tq via column-summed Wq).
#define PRODUCE_F(BUF, XP) do {                                               \
  float ls[16];                                                               \
  _Pragma("unroll") for (int t = 0; t < 16; ++t) {                            \
    float xs[7];                                                              \
    _Pragma("unroll") for (int jj = 0; jj < 7; ++jj) xs[jj] = (XP)[t * 7 + jj]; \
    float fp = bF2;                                                           \
    _Pragma("unroll") for (int jj = 0; jj < 7; ++jj) fp = fmaf(xs[jj], wf2[jj], fp); \
    const float ena = ex2(-fp);                                               \
    sFs[BUF][t][lane] = __fdividef(1.f, 1.f + ena);                           \
    ls[t] = (fp < GUARD2) ? fp : -lg2(1.f + ena);                             \
  }                                                                           \
  _Pragma("unroll") for (int t = 1; t < 16; ++t) ls[t] += ls[t - 1];          \
  sEM[BUF][lane]   = ex2(ls[7]);                                              \
  sFtot[BUF][lane] = ex2(ls[15]);                                             \
  sCF[BUF][lane]   = ex2(ls[15] - ls[7]);                                     \
  { const int tq = lane & 15;                                                 \
    float Sqv = wqs[7];                                                       \
    _Pragma("unroll") for (int jj = 0; jj < 7; ++jj)                          \
      Sqv = fmaf((XP)[tq * 7 + jj], wqs[jj], Sqv);                            \
    if (lane < 16) sSq[BUF][tq] = Sqv; }                                      \
} while (0)

// w7: q~ with own f (full prefix for the per-t scale).
#define PRODUCE_Q(BUF, XP) do {                                               \
  float qv[16], ls[16];                                                       \
  _Pragma("unroll") for (int t = 0; t < 16; ++t) {                            \
    float xs[7];                                                              \
    _Pragma("unroll") for (int jj = 0; jj < 7; ++jj) xs[jj] = (XP)[t * 7 + jj]; \
    float qq = bQ, fp = bF2;                                                  \
    _Pragma("unroll") for (int jj = 0; jj < 7; ++jj) {                        \
      qq = fmaf(xs[jj], wq[jj], qq); fp = fmaf(xs[jj], wf2[jj], fp);          \
    }                                                                         \
    qv[t] = qq;                                                               \
    ls[t] = logsig2(fp);                                                      \
  }                                                                           \
  _Pragma("unroll") for (int t = 1; t < 16; ++t) ls[t] += ls[t - 1];          \
  const float m = ls[7];                                                      \
  _Pragma("unroll") for (int t = 0; t < 16; ++t)                              \
    sQt[BUF][t][lane] = f2bf(qv[t] * ex2(ls[t] - m));                         \
} while (0)

// Single-barrier-per-chunk wave-specialized mLSTM. 512 threads = 8 waves/batch.
// All intra-chunk cross-wave LDS deps removed: private per-wave sS (each consumer
// wave holds full S), same-wave sC0 round-trip, n-scan moved into consumers
// (16 own channels each, reading sFs/sIK written one region earlier), per-lane
// o-projection (only the 4 t's each lane outputs). Producers one chunk ahead,
// self-contained (own f where needed); khat's global scale 2^{cl15-cl7} applied
// per-column in fp32 after the G MFMA. Barriers: B0 + 16 + final = 18 (was 33).
__global__ __launch_bounds__(512, 4) void mlstm_ws3(
    const float* __restrict__ x,
    const float* __restrict__ Cin,
    const float* __restrict__ nin,
    const float* __restrict__ Wq, const float* __restrict__ bq,
    const float* __restrict__ Wk, const float* __restrict__ bk,
    const float* __restrict__ Wv, const float* __restrict__ bv,
    const float* __restrict__ Wi, const float* __restrict__ bi,
    const float* __restrict__ Wf, const float* __restrict__ bf,
    const float* __restrict__ Wo, const float* __restrict__ bo,
    float* __restrict__ hout, float* __restrict__ Cout, float* __restrict__ nout)
{
  const int b    = blockIdx.x;
  const int tid  = threadIdx.x;
  const int lane = tid & 63;
  const int w    = __builtin_amdgcn_readfirstlane(tid >> 6);  // wave 0..7
  const int quad = lane >> 4;
  const int sl   = lane & 15;

  __shared__ __align__(16) unsigned short sQt[2][L_][72];     // q~ [t][c]
  __shared__ __align__(16) unsigned short sKt[2][L_][72];     // k~ [s][c]
  __shared__ __align__(16) unsigned short sVT[2][H_][40];     // v  [r][s] (s 16..31 zero)
  __shared__ __align__(16) unsigned short sKnT[2][H_][40];    // k~^T [c][s] (s 16..31 zero)
  __shared__ __align__(16) unsigned short sS[4][L_][40];      // PRIVATE masked S per consumer wave
  __shared__ __align__(16) unsigned short sC0[H_][72];        // C0*2^m [r][c] (same-wave rows)
  __shared__ float sFs[2][L_][H_];                            // sigmoid(f) [t][c]
  __shared__ float sIK[2][L_][H_];                            // i*k (scaled) [t][c]
  __shared__ float sSq[2][L_];                                // sum_r q_t[r]
  __shared__ float sEM[2][H_];                                // 2^{cl7}
  __shared__ float sFtot[2][H_];                              // 2^{cl15}
  __shared__ float sCF[2][H_];                                // 2^{cl15-cl7}
  __shared__ float sNv[H_];

  // zero pads: sVT/sKnT cols 16..31 (both buffers), entire private sS
  for (int idx = tid; idx < 1024; idx += 512) {
    const int bu = idx >> 9, r = (idx >> 3) & 63, d = idx & 7;
    ((unsigned*)sVT)[(bu * 64 + r) * 20 + 8 + d]  = 0;
    ((unsigned*)sKnT)[(bu * 64 + r) * 20 + 8 + d] = 0;
  }
  for (int idx = tid; idx < 1280; idx += 512) ((unsigned*)sS)[idx] = 0;

  const float* __restrict__ xb = x + (size_t)b * T_ * I_;

  if (w < 4) {
    // ================== CONSUMERS ==================
    const int c0 = 16 * w + sl;   // this lane's channel (C row / h channel / n col)
    float wOl[7];
#pragma unroll
    for (int jj = 0; jj < 7; ++jj) wOl[jj] = Wo[c0 * 7 + jj] * L2E;
    const float bO2 = bo[c0] * L2E;
    f32x4 Cacc[4];
#pragma unroll
    for (int ct = 0; ct < 4; ++ct)
#pragma unroll
      for (int reg = 0; reg < 4; ++reg)
        Cacc[ct][reg] =
            Cin[(size_t)b * H_ * H_ + (size_t)(16 * w + 4 * quad + reg) * H_ + 16 * ct + sl];
    float nv = nin[(size_t)b * H_ * H_ + c0];
    __syncthreads();  // B0
    for (int j = 0; j < NCH_; ++j) {
      const int p = j & 1;
      const float* xc = xb + (size_t)j * L_ * I_;
      // ---- n-scan for own channel (serial over t; den kept only at own 4 t's) ----
      float den4[4];
#pragma unroll
      for (int t = 0; t < 16; ++t) {
        const float fs  = sFs[p][t][c0];
        const float ikv = sIK[p][t][c0];
        nv = fmaf(fs, nv, ikv);
        if ((t >> 2) == quad) den4[t & 3] = nv;
      }
      float idn[4], oo[4];
#pragma unroll
      for (int r2 = 0; r2 < 4; ++r2) {
        const int t = 4 * quad + r2;
        idn[r2] = __fdividef(1.f, fmaxf(den4[r2] * sSq[p][t], 1.f));
        float op = bO2;
#pragma unroll
        for (int jj = 0; jj < 7; ++jj) op = fmaf(xc[t * 7 + jj], wOl[jj], op);
        oo[r2] = sig2(op);
      }
      // ---- S = Q~ K~^T (full 16x16 per wave), masked into private sS ----
      const bf16x8 aQ0 = *(const bf16x8*)&sQt[p][sl][8 * quad];
      const bf16x8 aQ1 = *(const bf16x8*)&sQt[p][sl][32 + 8 * quad];
      const bf16x8 bK0 = *(const bf16x8*)&sKt[p][sl][8 * quad];
      const bf16x8 bK1 = *(const bf16x8*)&sKt[p][sl][32 + 8 * quad];
      f32x4 Sv = {0.f, 0.f, 0.f, 0.f};
      Sv = __builtin_amdgcn_mfma_f32_16x16x32_bf16(aQ0, bK0, Sv, 0, 0, 0);
      Sv = __builtin_amdgcn_mfma_f32_16x16x32_bf16(aQ1, bK1, Sv, 0, 0, 0);
#pragma unroll
      for (int reg = 0; reg < 4; ++reg) {
        const int t = 4 * quad + reg;
        sS[w][t][sl] = f2bf((sl <= t) ? Sv[reg] : 0.f);
      }
      // ---- C0 snapshot (same-wave rows) + G = V k~^T ----
      const bf16x8 aV = *(const bf16x8*)&sVT[p][c0][8 * quad];
      f32x4 G[4];
      float ftA[4], cfA[4];
#pragma unroll
      for (int ct = 0; ct < 4; ++ct) {
        const int cc = 16 * ct + sl;
        const float emv = sEM[p][cc];
        ftA[ct] = sFtot[p][cc];
        cfA[ct] = sCF[p][cc];
#pragma unroll
        for (int reg = 0; reg < 4; ++reg)
          sC0[16 * w + 4 * quad + reg][cc] = f2bf(Cacc[ct][reg] * emv);
        const bf16x8 bKn = *(const bf16x8*)&sKnT[p][cc][8 * quad];
        f32x4 z = {0.f, 0.f, 0.f, 0.f};
        G[ct] = __builtin_amdgcn_mfma_f32_16x16x32_bf16(aV, bKn, z, 0, 0, 0);
      }
      // ---- Num = Q~ C0^T + (M.S) V^T (same-wave LDS round-trips) ----
      const bf16x8 bC0a = *(const bf16x8*)&sC0[c0][8 * quad];
      const bf16x8 bC0b = *(const bf16x8*)&sC0[c0][32 + 8 * quad];
      const bf16x8 aS   = *(const bf16x8*)&sS[w][sl][8 * quad];
      f32x4 Num = {0.f, 0.f, 0.f, 0.f};
      Num = __builtin_amdgcn_mfma_f32_16x16x32_bf16(aQ0, bC0a, Num, 0, 0, 0);
      Num = __builtin_amdgcn_mfma_f32_16x16x32_bf16(aQ1, bC0b, Num, 0, 0, 0);
      Num = __builtin_amdgcn_mfma_f32_16x16x32_bf16(aS, aV, Num, 0, 0, 0);
#pragma unroll
      for (int reg = 0; reg < 4; ++reg) {
        const int t = 4 * quad + reg;
        const float y = Num[reg] * idn[reg];
        const float e = ex2(y * 2.88539008178f);  // e^{2y}
        const float th = 1.f - __fdividef(2.f, e + 1.f);
        hout[(size_t)b * T_ * H_ + (size_t)(j * L_ + t) * H_ + c0] = oo[reg] * th;
      }
      // ---- C update: ft*C + cf*G (khat scale applied in fp32 here) ----
#pragma unroll
      for (int ct = 0; ct < 4; ++ct) Cacc[ct] = Cacc[ct] * ftA[ct] + G[ct] * cfA[ct];
      __syncthreads();
    }
#pragma unroll
    for (int ct = 0; ct < 4; ++ct)
#pragma unroll
      for (int reg = 0; reg < 4; ++reg)
        Cout[(size_t)b * H_ * H_ + (size_t)(16 * w + 4 * quad + reg) * H_ + 16 * ct + sl] =
            Cacc[ct][reg];
    if (quad == 0) sNv[c0] = nv;
  } else if (w == 4 || w == 5) {
    // ================== i,k,v producer (t-half) ==================
    const int tb = (w == 4) ? 0 : 8;
    float wi2[7], wk[7], wf2[7], wv[7];
#pragma unroll
    for (int jj = 0; jj < 7; ++jj) {
      wi2[jj] = Wi[lane * 7 + jj] * L2E;
      wk[jj]  = Wk[lane * 7 + jj];
      wf2[jj] = Wf[lane * 7 + jj] * L2E;
      wv[jj]  = Wv[lane * 7 + jj];
    }
    const float bI2 = bi[lane] * L2E, bK = bk[lane], bF2 = bf[lane] * L2E, bV = bv[lane];
    PRODUCE_IKV(0, xb);
    __syncthreads();  // B0
    for (int j = 0; j < NCH_; ++j) {
      if (j + 1 < NCH_) {
        const int pn = (j + 1) & 1;
        const float* xn = xb + (size_t)(j + 1) * L_ * I_;
        if (pn) PRODUCE_IKV(1, xn); else PRODUCE_IKV(0, xn);
      }
      __syncthreads();
    }
  } else if (w == 6) {
    // ================== f producer + Sq ==================
    float wf2[7], wqs[8];
#pragma unroll
    for (int jj = 0; jj < 7; ++jj) wf2[jj] = Wf[lane * 7 + jj] * L2E;
    const float bF2 = bf[lane] * L2E;
#pragma unroll
    for (int jj = 0; jj < 7; ++jj) {
      float s = 0.f;
      for (int r = 0; r < H_; ++r) s += Wq[r * 7 + jj];
      wqs[jj] = s;
    }
    {
      float s = 0.f;
      for (int r = 0; r < H_; ++r) s += bq[r];
      wqs[7] = s;
    }
    PRODUCE_F(0, xb);
    __syncthreads();  // B0
    for (int j = 0; j < NCH_; ++j) {
      if (j + 1 < NCH_) {
        const int pn = (j + 1) & 1;
        const float* xn = xb + (size_t)(j + 1) * L_ * I_;
        if (pn) PRODUCE_F(1, xn); else PRODUCE_F(0, xn);
      }
      __syncthreads();
    }
  } else {
    // ================== q producer (own f for the scale) ==================
    float wq[7], wf2[7];
#pragma unroll
    for (int jj = 0; jj < 7; ++jj) {
      wq[jj]  = Wq[lane * 7 + jj];
      wf2[jj] = Wf[lane * 7 + jj] * L2E;
    }
    const float bQ = bq[lane], bF2 = bf[lane] * L2E;
    PRODUCE_Q(0, xb);
    __syncthreads();  // B0
    for (int j = 0; j < NCH_; ++j) {
      if (j + 1 < NCH_) {
        const int pn = (j + 1) & 1;
        const float* xn = xb + (size_t)(j + 1) * L_ * I_;
        if (pn) PRODUCE_Q(1, xn); else PRODUCE_Q(0, xn);
      }
      __syncthreads();
    }
  }

  __syncthreads();  // final: sNv ready
  {
    const float nvv = sNv[lane];
#pragma unroll
    for (int k = 0; k < 8; ++k)
      nout[(size_t)b * H_ * H_ + (size_t)(8 * w + k) * H_ + lane] = nvv;
  }
}

extern "C" void kernel_launch(void* const* d_in, const int* in_sizes, int n_in,
                              void* d_out, int out_size, void* d_ws, size_t ws_size,
                              hipStream_t stream) {
  const float* xp  = (const float*)d_in[0];
  const float* Cp  = (const float*)d_in[1];
  const float* np_ = (const float*)d_in[2];

  const float* W[6];
  const float* Bv[6];
  if (n_in >= 15 && in_sizes[4] == 64) {
    for (int g = 0; g < 6; ++g) {
      W[g]  = (const float*)d_in[3 + 2 * g];
      Bv[g] = (const float*)d_in[4 + 2 * g];
    }
  } else {
    for (int g = 0; g < 6; ++g) {
      W[g]  = (const float*)d_in[3 + g];
      Bv[g] = (const float*)d_in[9 + g];
    }
  }

  float* hout = (float*)d_out;
  float* Cout = hout + (size_t)B_ * T_ * H_;
  float* nout = Cout + (size_t)B_ * H_ * H_;

  mlstm_ws3<<<dim3(B_), dim3(512), 0, stream>>>(
      xp, Cp, np_,
      W[0], Bv[0], W[1], Bv[1], W[2], Bv[2],
      W[3], Bv[3], W[4], Bv[4], W[5], Bv[5],
      hout, Cout, nout);
}